// Round 5
// baseline (275.595 us; speedup 1.0000x reference)
//
#include <hip/hip_runtime.h>
#include <hip/hip_bf16.h>
#include <hip/hip_cooperative_groups.h>
#include <stdint.h>

namespace cg = cooperative_groups;

typedef __attribute__((ext_vector_type(8))) short short8;
typedef __attribute__((ext_vector_type(4))) float f32x4;
typedef uint32_t u32;
typedef uint16_t u16;
typedef uint8_t u8;

#define LOG2E 1.4426950408889634f

// B=4, N=2048, Cin=256, F=64, H=4
// SINGLE cooperative kernel, 4 phases separated by grid.sync():
//  A: proj (x@W per head, MFMA, W transposed block-locally in LDS) + fused
//     exact-fp32 fdots -> Aarr/Barr/Cexp/Dexp  ||  pack adj bits  ||  Wlb cvt
//  B: colsum  D_j = sum_i bit*max(A_i*C_j, B_i*Dbar_j) -> CD packed bf16
//  C: pv  P in-register (32 i/wave, mask+CD from L2), j-split -> f32 partials
//  D: out = leaky(relu(p0+p1) @ Wl^T + bl)  (512 tasks of 16 rows)
//
// ws layout (bytes):
//  adjw : 0x0000000 u32[2048*64]        512KB packed adjacency bits
//  hT   : 0x0080000 bf16[16][64][2048]    4MB per-(b,h) h transposed [f][n]
//  part : 0x0480000 f32[2][4][2048][256] 16MB hp partial sums (2 j-halves)
//  Aarr : 0x1480000 f32[16][2048]       128KB exp2(f1*log2e)
//  Barr : 0x14A0000 f32                 128KB exp2(0.2*f1*log2e)
//  Cexp : 0x14C0000 f32                 128KB exp2(f2*log2e)
//  Dexp : 0x14E0000 f32                 128KB exp2(0.2*f2*log2e)
//  CD   : 0x1500000 u32[16][2048]       128KB packed (bf16 C/D | bf16 Dbar/D)
//  Wlb  : 0x1520000 bf16[64][256]        32KB

__device__ __forceinline__ u16 f2bf(float f){
  union{float f; u32 u;} x; x.f = f;
  u32 r = x.u + 0x7FFFu + ((x.u >> 16) & 1u);
  return (u16)(r >> 16);
}
__device__ __forceinline__ u32 pkbf(float a, float b){
  __hip_bfloat162 h = __float22bfloat162_rn(float2{a, b});
  union{ __hip_bfloat162 h; u32 u; } cv; cv.h = h;
  return cv.u;
}
__device__ __forceinline__ float bflo(u32 cd){ union{u32 u; float f;} v; v.u = cd << 16; return v.f; }
__device__ __forceinline__ float bfhi(u32 cd){ union{u32 u; float f;} v; v.u = cd & 0xFFFF0000u; return v.f; }

struct KP {
  const float* x; const int* adj; const float* W; const float* a1; const float* a2;
  const float* Wl; const float* bl; float* out;
  u32* adjw; u16* hT; float* part;
  float* Aarr; float* Barr; float* Cexp; float* Dexp; u32* CD; u16* Wlb;
};

__global__ __launch_bounds__(256, 2) void k_fused(KP p){
  cg::grid_group gg = cg::this_grid();
  const int nbid = gridDim.x;
  const int t = threadIdx.x;
  const int w = t >> 6, l = t & 63;

  __shared__ union SH {
    u16 WL[64*264];                                            // A: 33792B
    struct { float AL[2048]; float BL[2048]; float red[4][64]; } cs; // B: 17.4KB
    u16 hTl[64*136];                                           // C: 17.4KB
    u16 AD[16*272];                                            // D: 8.7KB
  } sh;

  // ================= Phase A =================
  // A1: proj + fdots (512 tasks: 128 row-tiles x 4 heads)
  for (int task = blockIdx.x; task < 512; task += nbid){
    __syncthreads();
    int rt = task & 127, cb = task >> 7;
    const float* Wh = p.W + (size_t)cb*16384;   // [256 c][64 f]
    #pragma unroll 4
    for (int pp = 0; pp < 16; pp++){
      int idx = pp*256 + t;
      float4 wv = ((const float4*)Wh)[idx];
      int off = idx*4; int c = off >> 6, f0 = off & 63;
      sh.WL[(f0+0)*264 + c] = f2bf(wv.x);
      sh.WL[(f0+1)*264 + c] = f2bf(wv.y);
      sh.WL[(f0+2)*264 + c] = f2bf(wv.z);
      sh.WL[(f0+3)*264 + c] = f2bf(wv.w);
    }
    __syncthreads();

    int rA = rt*64 + w*16 + (l & 15);
    int kg = (l >> 4) * 8;
    f32x4 acc[4] = {};
    const float* xrow = p.x + (size_t)rA * 256;
    #pragma unroll
    for (int ks = 0; ks < 8; ks++){
      int c = ks*32 + kg;
      float4 xa = *(const float4*)(xrow + c);
      float4 xb = *(const float4*)(xrow + c + 4);
      union{u32 w[4]; short8 v;} A;
      A.w[0] = pkbf(xa.x, xa.y); A.w[1] = pkbf(xa.z, xa.w);
      A.w[2] = pkbf(xb.x, xb.y); A.w[3] = pkbf(xb.z, xb.w);
      #pragma unroll
      for (int q = 0; q < 4; q++){
        short8 Bf = *(const short8*)&sh.WL[(q*16 + (l & 15))*264 + c];
        acc[q] = __builtin_amdgcn_mfma_f32_16x16x32_bf16(A.v, Bf, acc[q], 0, 0, 0);
      }
    }
    // store hT (bf16) [bh][f][n]
    int rb = rt*64 + w*16 + (l >> 4)*4;
    int b = rb >> 11, n = rb & 2047;
    #pragma unroll
    for (int q = 0; q < 4; q++){
      int f = q*16 + (l & 15);
      u32 p0 = pkbf(acc[q][0], acc[q][1]);
      u32 p1 = pkbf(acc[q][2], acc[q][3]);
      u16* dst = p.hT + ((size_t)(b*4 + cb)*64 + f)*2048 + n;
      *(uint2*)dst = uint2{p0, p1};
    }
    // fused fdots: exact fp32 f1/f2 from accumulators
    float a1v[4], a2v[4];
    #pragma unroll
    for (int q = 0; q < 4; q++){
      a1v[q] = p.a1[cb*64 + q*16 + (l & 15)];
      a2v[q] = p.a2[cb*64 + q*16 + (l & 15)];
    }
    float s1[4], s2[4];
    #pragma unroll
    for (int r = 0; r < 4; r++){
      s1[r] = acc[0][r]*a1v[0] + acc[1][r]*a1v[1] + acc[2][r]*a1v[2] + acc[3][r]*a1v[3];
      s2[r] = acc[0][r]*a2v[0] + acc[1][r]*a2v[1] + acc[2][r]*a2v[2] + acc[3][r]*a2v[3];
    }
    #pragma unroll
    for (int m = 1; m <= 8; m <<= 1){
      #pragma unroll
      for (int r = 0; r < 4; r++){
        s1[r] += __shfl_xor(s1[r], m);
        s2[r] += __shfl_xor(s2[r], m);
      }
    }
    if ((l & 15) == 0){
      #pragma unroll
      for (int r = 0; r < 4; r++){
        int row = rb + r;
        int bb = row >> 11, nn = row & 2047;
        int o = (bb*4 + cb)*2048 + nn;
        float fa = s1[r] * LOG2E;
        p.Aarr[o] = __builtin_amdgcn_exp2f(fa);
        p.Barr[o] = __builtin_amdgcn_exp2f(0.2f*fa);
        float fb = s2[r] * LOG2E;
        p.Cexp[o] = __builtin_amdgcn_exp2f(fb);
        p.Dexp[o] = __builtin_amdgcn_exp2f(0.2f*fb);
      }
    }
  }
  // A2: pack adj -> 1 u32 word per thread (131072 words total)
  for (int idx = blockIdx.x*256 + t; idx < 131072; idx += nbid*256){
    const int4* ap = (const int4*)(p.adj + (size_t)idx*32);
    u32 word = 0;
    #pragma unroll
    for (int k = 0; k < 8; k++){
      int4 v = ap[k];
      word |= ((u32)(v.x > 0) << (k*4))   | ((u32)(v.y > 0) << (k*4+1))
            | ((u32)(v.z > 0) << (k*4+2)) | ((u32)(v.w > 0) << (k*4+3));
    }
    p.adjw[idx] = word;
  }
  // A3: Wl -> bf16
  for (int i = blockIdx.x*256 + t; i < 16384; i += nbid*256) p.Wlb[i] = f2bf(p.Wl[i]);

  __threadfence();
  gg.sync();

  // ================= Phase B: colsum =================
  for (int task = blockIdx.x; task < 512; task += nbid){
    __syncthreads();
    int jt = task & 31, bh = task >> 5;
    {
      const float4* As = (const float4*)(p.Aarr + bh*2048);
      const float4* Bs = (const float4*)(p.Barr + bh*2048);
      ((float4*)sh.cs.AL)[t]       = As[t];
      ((float4*)sh.cs.AL)[t + 256] = As[t + 256];
      ((float4*)sh.cs.BL)[t]       = Bs[t];
      ((float4*)sh.cs.BL)[t + 256] = Bs[t + 256];
    }
    int j = jt*64 + l;
    float Cj = p.Cexp[bh*2048 + j];
    float Dj = p.Dexp[bh*2048 + j];
    int wi = jt*2 + (l >> 5);
    int shl = 31 - (l & 31);
    __syncthreads();
    const u32* aw = p.adjw + wi;
    float acc0 = 0.f, acc1 = 0.f;
    int i0 = w * 512;
    #pragma unroll 2
    for (int i = i0; i < i0 + 512; i += 8){
      float av[8], bv[8];
      *(float4*)(av)   = *(const float4*)&sh.cs.AL[i];
      *(float4*)(av+4) = *(const float4*)&sh.cs.AL[i+4];
      *(float4*)(bv)   = *(const float4*)&sh.cs.BL[i];
      *(float4*)(bv+4) = *(const float4*)&sh.cs.BL[i+4];
      u32 m[8];
      #pragma unroll
      for (int k = 0; k < 8; k++) m[k] = aw[(size_t)(i+k)*64];
      #pragma unroll
      for (int k = 0; k < 8; k++){
        float v = fmaxf(av[k]*Cj, bv[k]*Dj);
        float sel = ((int)(m[k] << shl) < 0) ? v : 0.f;
        if (k & 1) acc1 += sel; else acc0 += sel;
      }
    }
    sh.cs.red[w][l] = acc0 + acc1;
    __syncthreads();
    if (t < 64){
      float D = (sh.cs.red[0][l] + sh.cs.red[1][l]) + (sh.cs.red[2][l] + sh.cs.red[3][l]);
      float inv = 1.0f / D;
      p.CD[bh*2048 + j] = pkbf(Cj * inv, Dj * inv);
    }
  }

  __threadfence();
  gg.sync();

  // ================= Phase C: pv =================
  for (int task = blockIdx.x; task < 512; task += nbid){
    int it = task & 15, bh = (task >> 4) & 15, jh = task >> 8;
    int b = bh >> 2, h = bh & 3;

    int i0 = it*128 + w*32 + (l & 15);
    float Ai0 = p.Aarr[bh*2048 + i0],      Bi0 = p.Barr[bh*2048 + i0];
    float Ai1 = p.Aarr[bh*2048 + i0 + 16], Bi1 = p.Barr[bh*2048 + i0 + 16];
    const u32* CDr = p.CD + bh*2048;
    const u16* hTr = p.hT + (size_t)bh * 64 * 2048;
    int kg = (l >> 4) * 8;
    f32x4 acc[2][4] = {};

    for (int jj = 0; jj < 1024; jj += 128){
      int jc = jh*1024 + jj;
      __syncthreads();
      {  // stage hT tile [64 f][128 j]
        int f = t >> 2, seg = (t & 3) * 32;
        const u16* src = hTr + (size_t)f*2048 + jc + seg;
        u16* d = sh.hTl + f*136 + seg;
        *(uint4*)(d)      = *(const uint4*)(src);
        *(uint4*)(d + 8)  = *(const uint4*)(src + 8);
        *(uint4*)(d + 16) = *(const uint4*)(src + 16);
        *(uint4*)(d + 24) = *(const uint4*)(src + 24);
      }
      __syncthreads();
      uint4 mw0 = *(const uint4*)(p.adjw + (size_t)i0*64 + (jc >> 5));
      uint4 mw1 = *(const uint4*)(p.adjw + (size_t)(i0+16)*64 + (jc >> 5));
      #pragma unroll
      for (int ks = 0; ks < 4; ks++){
        u32 cd[8];
        *(uint4*)(cd)     = *(const uint4*)(CDr + jc + ks*32 + kg);
        *(uint4*)(cd + 4) = *(const uint4*)(CDr + jc + ks*32 + kg + 4);
        u32 w0 = (&mw0.x)[ks] >> kg;
        u32 w1 = (&mw1.x)[ks] >> kg;
        float wv0[8], wv1[8];
        #pragma unroll
        for (int e = 0; e < 8; e++){
          float ca = bflo(cd[e]), db = bfhi(cd[e]);
          float ev0 = fmaxf(Ai0*ca, Bi0*db);
          float ev1 = fmaxf(Ai1*ca, Bi1*db);
          wv0[e] = ((int)(w0 << (31-e)) < 0) ? ev0 : 0.f;
          wv1[e] = ((int)(w1 << (31-e)) < 0) ? ev1 : 0.f;
        }
        union{u32 w[4]; short8 v;} A0, A1;
        A0.w[0] = pkbf(wv0[0], wv0[1]); A0.w[1] = pkbf(wv0[2], wv0[3]);
        A0.w[2] = pkbf(wv0[4], wv0[5]); A0.w[3] = pkbf(wv0[6], wv0[7]);
        A1.w[0] = pkbf(wv1[0], wv1[1]); A1.w[1] = pkbf(wv1[2], wv1[3]);
        A1.w[2] = pkbf(wv1[4], wv1[5]); A1.w[3] = pkbf(wv1[6], wv1[7]);
        #pragma unroll
        for (int q = 0; q < 4; q++){
          short8 Bf = *(const short8*)&sh.hTl[(q*16 + (l & 15))*136 + ks*32 + kg];
          acc[0][q] = __builtin_amdgcn_mfma_f32_16x16x32_bf16(A0.v, Bf, acc[0][q], 0, 0, 0);
          acc[1][q] = __builtin_amdgcn_mfma_f32_16x16x32_bf16(A1.v, Bf, acc[1][q], 0, 0, 0);
        }
      }
    }
    // write f32 partials [jh][b][n][h*64+f]
    float* pr = p.part + ((size_t)(jh*4 + b)*2048)*256;
    #pragma unroll
    for (int r = 0; r < 2; r++){
      int nb = it*128 + w*32 + r*16 + (l >> 4)*4;
      #pragma unroll
      for (int q = 0; q < 4; q++){
        int f = h*64 + q*16 + (l & 15);
        #pragma unroll
        for (int rr = 0; rr < 4; rr++){
          pr[(size_t)(nb + rr)*256 + f] = acc[r][q][rr];
        }
      }
    }
  }

  __threadfence();
  gg.sync();

  // ================= Phase D: out (512 tasks of 16 rows) =================
  for (int task = blockIdx.x; task < 512; task += nbid){
    __syncthreads();
    int r0 = task*16;
    {
      int row = t >> 4, cs0 = (t & 15)*16;
      int gr = r0 + row; int b = gr >> 11, n = gr & 2047;
      const float* p0 = p.part + ((size_t)(b*2048) + n)*256 + cs0;
      const float* p1 = p.part + ((size_t)((4+b)*2048) + n)*256 + cs0;
      float av[16];
      #pragma unroll
      for (int k = 0; k < 4; k++){
        float4 u0 = *(const float4*)(p0 + k*4);
        float4 u1 = *(const float4*)(p1 + k*4);
        av[k*4+0] = fmaxf(u0.x + u1.x, 0.f);
        av[k*4+1] = fmaxf(u0.y + u1.y, 0.f);
        av[k*4+2] = fmaxf(u0.z + u1.z, 0.f);
        av[k*4+3] = fmaxf(u0.w + u1.w, 0.f);
      }
      u32 pk[8];
      #pragma unroll
      for (int k = 0; k < 8; k++) pk[k] = pkbf(av[2*k], av[2*k+1]);
      u16* d = &sh.AD[row*272 + cs0];
      *(uint4*)(d)     = *(uint4*)(pk);
      *(uint4*)(d + 8) = *(uint4*)(pk + 4);
    }
    __syncthreads();
    int kg = (l >> 4) * 8;
    f32x4 acc = {};
    #pragma unroll
    for (int ks = 0; ks < 8; ks++){
      int c = ks*32 + kg;
      short8 Af = *(const short8*)&sh.AD[(l & 15)*272 + c];
      short8 Bf = *(const short8*)(p.Wlb + (size_t)(w*16 + (l & 15))*256 + c);
      acc = __builtin_amdgcn_mfma_f32_16x16x32_bf16(Af, Bf, acc, 0, 0, 0);
    }
    float bv = p.bl[w*16 + (l & 15)];
    #pragma unroll
    for (int r = 0; r < 4; r++){
      float v = acc[r] + bv;
      int gr = r0 + (l >> 4)*4 + r;
      p.out[(size_t)gr*64 + w*16 + (l & 15)] = fmaxf(v, 0.2f*v);
    }
  }
}

extern "C" void kernel_launch(void* const* d_in, const int* in_sizes, int n_in,
                              void* d_out, int out_size, void* d_ws, size_t ws_size,
                              hipStream_t stream) {
  char* ws = (char*)d_ws;
  KP kp;
  kp.x    = (const float*)d_in[0];
  kp.adj  = (const int*)d_in[1];
  kp.W    = (const float*)d_in[2];
  kp.a1   = (const float*)d_in[3];
  kp.a2   = (const float*)d_in[4];
  kp.Wl   = (const float*)d_in[5];
  kp.bl   = (const float*)d_in[6];
  kp.out  = (float*)d_out;
  kp.adjw = (u32*)(ws + 0x0000000);
  kp.hT   = (u16*)(ws + 0x0080000);
  kp.part = (float*)(ws + 0x0480000);
  kp.Aarr = (float*)(ws + 0x1480000);
  kp.Barr = (float*)(ws + 0x14A0000);
  kp.Cexp = (float*)(ws + 0x14C0000);
  kp.Dexp = (float*)(ws + 0x14E0000);
  kp.CD   = (u32*)(ws + 0x1500000);
  kp.Wlb  = (u16*)(ws + 0x1520000);

  int maxb = 0;
  if (hipOccupancyMaxActiveBlocksPerMultiprocessor(&maxb, k_fused, 256, 0) != hipSuccess || maxb < 1)
    maxb = 1;
  int grid = maxb * 256;          // 256 CUs on MI355X
  if (grid > 512) grid = 512;

  void* args[] = { &kp };
  hipLaunchCooperativeKernel((void*)k_fused, dim3(grid), dim3(256), args, 0, stream);
}

// Round 6
// 149.390 us; speedup vs baseline: 1.8448x; 1.8448x over previous
//
#include <hip/hip_runtime.h>
#include <hip/hip_bf16.h>
#include <stdint.h>

typedef __attribute__((ext_vector_type(8))) short short8;
typedef __attribute__((ext_vector_type(4))) float f32x4;
typedef uint32_t u32;
typedef uint16_t u16;
typedef uint8_t u8;

#define LOG2E 1.4426950408889634f

// B=4, N=2048, Cin=256, F=64, H=4
// Pipeline (4 kernels, R4 skeleton + WL swizzle + colsum uint4):
//  K1 k_front : proj (x@W per head via MFMA, W transposed block-locally in LDS,
//               XOR-swizzled to kill bank conflicts) + fused exact-fp32 fdots
//               -> Aarr/Barr/Cexp/Dexp  ||  pack adj bits
//  K2 k_colsum: D_j = sum_i bit*max(A_i*C_j, B_i*Dbar_j); 128 j per block,
//               mask via one uint4 load per 4 i -> CD packed bf16
//  K3 k_pv    : P in-register (32 i/wave, mask+CD from L2, B-frags reused 2x),
//               j-split halves -> f32 partials
//  K4 k_out   : out = leaky((relu(p0+p1) @ Wl^T) + bl), Wl converted inline
//
// ws layout (bytes):
//  adjw : 0x0000000 u32[2048*64]       512KB  packed adjacency bits
//  hT   : 0x0080000 bf16[16][64][2048]   4MB  per-(b,h) h transposed [f][n]
//  part : 0x0480000 f32[2][4][2048][256] 16MB hp partial sums (2 j-halves)
//  Aarr : 0x1480000 f32[16][2048]      128KB  exp2(f1*log2e)
//  Barr : 0x14A0000 f32                128KB  exp2(0.2*f1*log2e)
//  Cexp : 0x14C0000 f32                128KB  exp2(f2*log2e)
//  Dexp : 0x14E0000 f32                128KB  exp2(0.2*f2*log2e)
//  CD   : 0x1500000 u32[16][2048]      128KB  packed (bf16 C/D | bf16 Dbar/D)

__device__ __forceinline__ u16 f2bf(float f){
  union{float f; u32 u;} x; x.f = f;
  u32 r = x.u + 0x7FFFu + ((x.u >> 16) & 1u);
  return (u16)(r >> 16);
}
__device__ __forceinline__ u32 pkbf(float a, float b){
  __hip_bfloat162 h = __float22bfloat162_rn(float2{a, b});
  union{ __hip_bfloat162 h; u32 u; } cv; cv.h = h;
  return cv.u;
}
__device__ __forceinline__ float bflo(u32 cd){ union{u32 u; float f;} v; v.u = cd << 16; return v.f; }
__device__ __forceinline__ float bfhi(u32 cd){ union{u32 u; float f;} v; v.u = cd & 0xFFFF0000u; return v.f; }

// ---------------- K1: proj(+fdots) || pack ----------------
__global__ __launch_bounds__(256) void k_front(const float* __restrict__ x,
      const float* __restrict__ W, const float* __restrict__ a1, const float* __restrict__ a2,
      const int* __restrict__ adj,
      u8* __restrict__ adjb, u16* __restrict__ hT,
      float* __restrict__ Aarr, float* __restrict__ Barr,
      float* __restrict__ Cexp, float* __restrict__ Dexp){
  int bid = blockIdx.x, t = threadIdx.x;

  if (bid >= 512){                    // ---- pack: 8 adj elems -> 1 byte ----
    int idx = (bid - 512)*256 + t;
    const int4* ap = (const int4*)(adj + (size_t)idx*8);
    int4 v0 = ap[0], v1 = ap[1];
    u32 byte = (u32)(v0.x > 0)        | ((u32)(v0.y > 0) << 1)
             | ((u32)(v0.z > 0) << 2) | ((u32)(v0.w > 0) << 3)
             | ((u32)(v1.x > 0) << 4) | ((u32)(v1.y > 0) << 5)
             | ((u32)(v1.z > 0) << 6) | ((u32)(v1.w > 0) << 7);
    adjb[idx] = (u8)byte;
    return;
  }
  // ---- proj: h = x @ W[head cb]; block-local W transpose in LDS, XOR-swizzled ----
  // swizzle: element (f, c) stored at WL[f*264 + (c ^ (((f>>2)&7)<<3))]
  // (XOR in units of 8 u16 = 16B keeps b128 reads aligned+contiguous)
  __shared__ u16 WL[64*264];
  int rt = bid & 127, cb = bid >> 7;
  const float* Wh = W + (size_t)cb*16384;     // [256 c][64 f]
  #pragma unroll 4
  for (int p = 0; p < 16; p++){
    int idx = p*256 + t;              // float4 index over 16384 f32
    float4 wv = ((const float4*)Wh)[idx];
    int off = idx*4; int c = off >> 6, f0 = off & 63;
    int cc = c ^ (((f0 >> 2) & 7) << 3);     // f0..f0+3 share f0>>2
    WL[(f0+0)*264 + cc] = f2bf(wv.x);
    WL[(f0+1)*264 + cc] = f2bf(wv.y);
    WL[(f0+2)*264 + cc] = f2bf(wv.z);
    WL[(f0+3)*264 + cc] = f2bf(wv.w);
  }
  __syncthreads();

  int w = t >> 6, l = t & 63;
  int rA = rt*64 + w*16 + (l & 15);
  int kg = (l >> 4) * 8;
  int rowq[4], rswq[4];
  #pragma unroll
  for (int q = 0; q < 4; q++){
    rowq[q] = q*16 + (l & 15);
    rswq[q] = ((rowq[q] >> 2) & 7) << 3;
  }
  f32x4 acc[4] = {};
  const float* xrow = x + (size_t)rA * 256;
  #pragma unroll
  for (int ks = 0; ks < 8; ks++){
    int c = ks*32 + kg;
    float4 xa = *(const float4*)(xrow + c);
    float4 xb = *(const float4*)(xrow + c + 4);
    union{u32 w[4]; short8 v;} A;
    A.w[0] = pkbf(xa.x, xa.y); A.w[1] = pkbf(xa.z, xa.w);
    A.w[2] = pkbf(xb.x, xb.y); A.w[3] = pkbf(xb.z, xb.w);
    #pragma unroll
    for (int q = 0; q < 4; q++){
      short8 Bf = *(const short8*)&WL[rowq[q]*264 + (c ^ rswq[q])];
      acc[q] = __builtin_amdgcn_mfma_f32_16x16x32_bf16(A.v, Bf, acc[q], 0, 0, 0);
    }
  }
  // store hT (bf16) [bh][f][n]
  int rb = rt*64 + w*16 + (l >> 4)*4;
  int b = rb >> 11, n = rb & 2047;
  #pragma unroll
  for (int q = 0; q < 4; q++){
    int f = q*16 + (l & 15);
    u32 p0 = pkbf(acc[q][0], acc[q][1]);
    u32 p1 = pkbf(acc[q][2], acc[q][3]);
    u16* dst = hT + ((size_t)(b*4 + cb)*64 + f)*2048 + n;
    *(uint2*)dst = uint2{p0, p1};
  }
  // fused fdots: exact fp32 f1/f2 from accumulators
  float a1v[4], a2v[4];
  #pragma unroll
  for (int q = 0; q < 4; q++){
    a1v[q] = a1[cb*64 + q*16 + (l & 15)];
    a2v[q] = a2[cb*64 + q*16 + (l & 15)];
  }
  float s1[4], s2[4];
  #pragma unroll
  for (int r = 0; r < 4; r++){
    s1[r] = acc[0][r]*a1v[0] + acc[1][r]*a1v[1] + acc[2][r]*a1v[2] + acc[3][r]*a1v[3];
    s2[r] = acc[0][r]*a2v[0] + acc[1][r]*a2v[1] + acc[2][r]*a2v[2] + acc[3][r]*a2v[3];
  }
  #pragma unroll
  for (int m = 1; m <= 8; m <<= 1){
    #pragma unroll
    for (int r = 0; r < 4; r++){
      s1[r] += __shfl_xor(s1[r], m);
      s2[r] += __shfl_xor(s2[r], m);
    }
  }
  if ((l & 15) == 0){
    #pragma unroll
    for (int r = 0; r < 4; r++){
      int row = rb + r;
      int bb = row >> 11, nn = row & 2047;
      int o = (bb*4 + cb)*2048 + nn;
      float fa = s1[r] * LOG2E;
      Aarr[o] = __builtin_amdgcn_exp2f(fa);
      Barr[o] = __builtin_amdgcn_exp2f(0.2f*fa);
      float fb = s2[r] * LOG2E;
      Cexp[o] = __builtin_amdgcn_exp2f(fb);
      Dexp[o] = __builtin_amdgcn_exp2f(0.2f*fb);
    }
  }
}

// ---------------- K2: colsum (128 j/block, uint4 mask loads) -> CD ----------------
__global__ __launch_bounds__(256) void k_colsum(const u32* __restrict__ adjw,
      const float* __restrict__ Aarr, const float* __restrict__ Barr,
      const float* __restrict__ Cexp, const float* __restrict__ Dexp,
      u32* __restrict__ CD){
  __shared__ float AL[2048], BL[2048];
  __shared__ float red[4][128];
  int jt = blockIdx.x;      // 16 tiles of 128 j
  int bh = blockIdx.y;      // 16
  int t = threadIdx.x;
  int w = t >> 6, l = t & 63;
  {
    const float4* As = (const float4*)(Aarr + bh*2048);
    const float4* Bs = (const float4*)(Barr + bh*2048);
    ((float4*)AL)[t]       = As[t];
    ((float4*)AL)[t + 256] = As[t + 256];
    ((float4*)BL)[t]       = Bs[t];
    ((float4*)BL)[t + 256] = Bs[t + 256];
  }
  int ja = jt*128 + l;                 // lane's first j
  int jb = ja + 64;                    // lane's second j
  float Cja = Cexp[bh*2048 + ja], Dja = Dexp[bh*2048 + ja];
  float Cjb = Cexp[bh*2048 + jb], Djb = Dexp[bh*2048 + jb];
  bool hiw = (l & 32) != 0;            // word select within pair
  int shr = l & 31;
  __syncthreads();
  // mask row i, words jt*4 .. jt*4+3 as one uint4
  const uint4* aw4 = (const uint4*)adjw + jt;   // element i at aw4[i*16]
  float aa0 = 0.f, aa1 = 0.f, ab0 = 0.f, ab1 = 0.f;
  int i0 = w * 512;
  #pragma unroll 2
  for (int i = i0; i < i0 + 512; i += 4){
    uint4 m0 = aw4[(size_t)(i+0)*16];
    uint4 m1 = aw4[(size_t)(i+1)*16];
    uint4 m2 = aw4[(size_t)(i+2)*16];
    uint4 m3 = aw4[(size_t)(i+3)*16];
    float av[4], bv[4];
    *(float4*)(av) = *(const float4*)&AL[i];
    *(float4*)(bv) = *(const float4*)&BL[i];
    uint4 mm[4] = {m0, m1, m2, m3};
    #pragma unroll
    for (int k = 0; k < 4; k++){
      u32 wa = hiw ? mm[k].y : mm[k].x;
      u32 wb = hiw ? mm[k].w : mm[k].z;
      float va = fmaxf(av[k]*Cja, bv[k]*Dja);
      float vb = fmaxf(av[k]*Cjb, bv[k]*Djb);
      float ba = (float)((wa >> shr) & 1u);
      float bb2 = (float)((wb >> shr) & 1u);
      if (k & 1){ aa1 = fmaf(va, ba, aa1); ab1 = fmaf(vb, bb2, ab1); }
      else      { aa0 = fmaf(va, ba, aa0); ab0 = fmaf(vb, bb2, ab0); }
    }
  }
  red[w][l]      = aa0 + aa1;
  red[w][64 + l] = ab0 + ab1;
  __syncthreads();
  if (t < 128){
    float D = (red[0][t] + red[1][t]) + (red[2][t] + red[3][t]);
    int j = jt*128 + t;
    float Cj = Cexp[bh*2048 + j], Dj = Dexp[bh*2048 + j];
    float inv = 1.0f / D;
    CD[bh*2048 + j] = pkbf(Cj * inv, Dj * inv);
  }
}

// ---------------- K3: fused PV, 32 i/wave, j-split -> f32 partials ----------------
__global__ __launch_bounds__(256) void k_pv(const u32* __restrict__ adjw, const u16* __restrict__ hT,
      const float* __restrict__ Aarr, const float* __restrict__ Barr,
      const u32* __restrict__ CD, float* __restrict__ part){
  int it = blockIdx.x;           // 16 i-tiles of 128
  int bh = blockIdx.y;           // 16
  int jh = blockIdx.z;           // 2 j-halves
  int b = bh >> 2, h = bh & 3;
  int t = threadIdx.x;
  int w = t >> 6, l = t & 63;

  __shared__ u16 hTl[64*136];         // 17.4KB, [f][j] padded stride 136 bf16

  int i0 = it*128 + w*32 + (l & 15);  // row-block 0; row-block 1 = i0+16
  float Ai0 = Aarr[bh*2048 + i0],      Bi0 = Barr[bh*2048 + i0];
  float Ai1 = Aarr[bh*2048 + i0 + 16], Bi1 = Barr[bh*2048 + i0 + 16];
  const u32* CDr = CD + bh*2048;
  const u16* hTr = hT + (size_t)bh * 64 * 2048;
  int kg = (l >> 4) * 8;
  f32x4 acc[2][4] = {};

  for (int jj = 0; jj < 1024; jj += 128){
    int jc = jh*1024 + jj;
    __syncthreads();
    {  // stage hT tile [64 f][128 j]
      int f = t >> 2, seg = (t & 3) * 32;
      const u16* src = hTr + (size_t)f*2048 + jc + seg;
      u16* d = hTl + f*136 + seg;
      *(uint4*)(d)      = *(const uint4*)(src);
      *(uint4*)(d + 8)  = *(const uint4*)(src + 8);
      *(uint4*)(d + 16) = *(const uint4*)(src + 16);
      *(uint4*)(d + 24) = *(const uint4*)(src + 24);
    }
    __syncthreads();
    uint4 mw0 = *(const uint4*)(adjw + (size_t)i0*64 + (jc >> 5));
    uint4 mw1 = *(const uint4*)(adjw + (size_t)(i0+16)*64 + (jc >> 5));
    #pragma unroll
    for (int ks = 0; ks < 4; ks++){
      u32 cd[8];
      *(uint4*)(cd)     = *(const uint4*)(CDr + jc + ks*32 + kg);
      *(uint4*)(cd + 4) = *(const uint4*)(CDr + jc + ks*32 + kg + 4);
      u32 w0 = (&mw0.x)[ks] >> kg;
      u32 w1 = (&mw1.x)[ks] >> kg;
      float wv0[8], wv1[8];
      #pragma unroll
      for (int e = 0; e < 8; e++){
        float ca = bflo(cd[e]), db = bfhi(cd[e]);
        float ev0 = fmaxf(Ai0*ca, Bi0*db);
        float ev1 = fmaxf(Ai1*ca, Bi1*db);
        wv0[e] = ((int)(w0 << (31-e)) < 0) ? ev0 : 0.f;
        wv1[e] = ((int)(w1 << (31-e)) < 0) ? ev1 : 0.f;
      }
      union{u32 w[4]; short8 v;} A0, A1;
      A0.w[0] = pkbf(wv0[0], wv0[1]); A0.w[1] = pkbf(wv0[2], wv0[3]);
      A0.w[2] = pkbf(wv0[4], wv0[5]); A0.w[3] = pkbf(wv0[6], wv0[7]);
      A1.w[0] = pkbf(wv1[0], wv1[1]); A1.w[1] = pkbf(wv1[2], wv1[3]);
      A1.w[2] = pkbf(wv1[4], wv1[5]); A1.w[3] = pkbf(wv1[6], wv1[7]);
      #pragma unroll
      for (int q = 0; q < 4; q++){
        short8 Bf = *(const short8*)&hTl[(q*16 + (l & 15))*136 + ks*32 + kg];
        acc[0][q] = __builtin_amdgcn_mfma_f32_16x16x32_bf16(A0.v, Bf, acc[0][q], 0, 0, 0);
        acc[1][q] = __builtin_amdgcn_mfma_f32_16x16x32_bf16(A1.v, Bf, acc[1][q], 0, 0, 0);
      }
    }
  }
  // epilogue: write f32 partial [jh][b][n][h*64+f]
  float* pr = part + ((size_t)(jh*4 + b)*2048)*256;
  #pragma unroll
  for (int r = 0; r < 2; r++){
    int nb = it*128 + w*32 + r*16 + (l >> 4)*4;
    #pragma unroll
    for (int q = 0; q < 4; q++){
      int f = h*64 + q*16 + (l & 15);
      #pragma unroll
      for (int rr = 0; rr < 4; rr++){
        pr[(size_t)(nb + rr)*256 + f] = acc[r][q][rr];
      }
    }
  }
}

// ---------------- K4: out = leaky(relu(p0+p1) @ Wl^T + bl) ----------------
__global__ __launch_bounds__(256) void k_out(const float* __restrict__ part,
                       const float* __restrict__ Wl, const float* __restrict__ bl,
                       float* __restrict__ out){
  int rt = blockIdx.x;   // 128 row tiles
  int w = threadIdx.x >> 6, l = threadIdx.x & 63;
  int rA = rt*64 + w*16 + (l & 15);
  int b = rA >> 11, n = rA & 2047;
  const float* p0 = part + ((size_t)b*2048 + n)*256;
  const float* p1 = part + ((size_t)(4 + b)*2048 + n)*256;
  int kg = (l >> 4) * 8;
  f32x4 acc[4] = {};
  #pragma unroll
  for (int ks = 0; ks < 8; ks++){
    int c = ks*32 + kg;
    float4 x0 = *(const float4*)(p0 + c);
    float4 x1 = *(const float4*)(p0 + c + 4);
    float4 y0 = *(const float4*)(p1 + c);
    float4 y1 = *(const float4*)(p1 + c + 4);
    float av[8];
    av[0] = fmaxf(x0.x + y0.x, 0.f); av[1] = fmaxf(x0.y + y0.y, 0.f);
    av[2] = fmaxf(x0.z + y0.z, 0.f); av[3] = fmaxf(x0.w + y0.w, 0.f);
    av[4] = fmaxf(x1.x + y1.x, 0.f); av[5] = fmaxf(x1.y + y1.y, 0.f);
    av[6] = fmaxf(x1.z + y1.z, 0.f); av[7] = fmaxf(x1.w + y1.w, 0.f);
    union{u32 w[4]; short8 v;} A;
    A.w[0] = pkbf(av[0], av[1]); A.w[1] = pkbf(av[2], av[3]);
    A.w[2] = pkbf(av[4], av[5]); A.w[3] = pkbf(av[6], av[7]);
    #pragma unroll
    for (int q = 0; q < 4; q++){
      const float* wr = Wl + (size_t)(q*16 + (l & 15))*256 + c;
      float4 u0 = *(const float4*)(wr);
      float4 u1 = *(const float4*)(wr + 4);
      union{u32 w[4]; short8 v;} Bv;
      Bv.w[0] = pkbf(u0.x, u0.y); Bv.w[1] = pkbf(u0.z, u0.w);
      Bv.w[2] = pkbf(u1.x, u1.y); Bv.w[3] = pkbf(u1.z, u1.w);
      acc[q] = __builtin_amdgcn_mfma_f32_16x16x32_bf16(A.v, Bv.v, acc[q], 0, 0, 0);
    }
  }
  int rb = rt*64 + w*16 + (l >> 4)*4;
  #pragma unroll
  for (int q = 0; q < 4; q++){
    int o = q*16 + (l & 15);
    float bv = bl[o];
    #pragma unroll
    for (int r = 0; r < 4; r++){
      float v = acc[q][r] + bv;
      out[(size_t)(rb + r)*64 + o] = fmaxf(v, 0.2f*v);
    }
  }
}

extern "C" void kernel_launch(void* const* d_in, const int* in_sizes, int n_in,
                              void* d_out, int out_size, void* d_ws, size_t ws_size,
                              hipStream_t stream) {
  const float* x  = (const float*)d_in[0];
  const int* adj  = (const int*)d_in[1];
  const float* W  = (const float*)d_in[2];
  const float* a1 = (const float*)d_in[3];
  const float* a2 = (const float*)d_in[4];
  const float* Wl = (const float*)d_in[5];
  const float* bl = (const float*)d_in[6];
  float* out = (float*)d_out;
  char* ws = (char*)d_ws;

  u32* adjw   = (u32*)(ws + 0x0000000);
  u16* hT     = (u16*)(ws + 0x0080000);
  float* part = (float*)(ws + 0x0480000);
  float* Aarr = (float*)(ws + 0x1480000);
  float* Barr = (float*)(ws + 0x14A0000);
  float* Cexp = (float*)(ws + 0x14C0000);
  float* Dexp = (float*)(ws + 0x14E0000);
  u32* CD     = (u32*)(ws + 0x1500000);

  k_front<<<2560, 256, 0, stream>>>(x, W, a1, a2, adj, (u8*)adjw, hT, Aarr, Barr, Cexp, Dexp);
  k_colsum<<<dim3(16, 16), 256, 0, stream>>>(adjw, Aarr, Barr, Cexp, Dexp, CD);
  k_pv<<<dim3(16, 16, 2), 256, 0, stream>>>(adjw, hT, Aarr, Barr, CD, part);
  k_out<<<128, 256, 0, stream>>>(part, Wl, bl, out);
}

// Round 7
// 77.660 us; speedup vs baseline: 3.5487x; 1.9236x over previous
//
#include <hip/hip_runtime.h>
#include <hip/hip_bf16.h>
#include <stdint.h>

typedef __attribute__((ext_vector_type(8))) short short8;
typedef __attribute__((ext_vector_type(4))) float f32x4;
typedef uint32_t u32;
typedef uint16_t u16;
typedef uint8_t u8;

#define LOG2E 1.4426950408889634f

// B=4, N=2048, Cin=256, F=64, H=4
// Pipeline (5 kernels):
//  K1 k_front : proj (x@W per head via MFMA, W transposed block-locally in LDS,
//               XOR-swizzled) + fused exact-fp32 fdots -> Aarr/Barr/Cexp/Dexp || pack adj
//  K2 k_colsum: partial D sums; block (jt, iseg) owns 64 j x 128 i x ALL 16 bh,
//               inner loop over bh (67 VALU per mask load -> VALU-bound)
//  K3 k_cd    : D = sum of 16 partials; CD = pkbf(C/D, Dbar/D)
//  K4 k_pv    : P in-register (32 i/wave, mask+CD from L2), j-split -> f32 partials
//  K5 k_out   : out = leaky((relu(p0+p1) @ Wl^T) + bl)
//
// ws layout (bytes):
//  adjw : 0x0000000 u32[2048*64]       512KB  packed adjacency bits
//  hT   : 0x0080000 bf16[16][64][2048]   4MB  per-(b,h) h transposed [f][n]
//  part : 0x0480000 f32[2][4][2048][256] 16MB pv partials (2 j-halves);
//         first 2MB double as colsum partials f32[16][16][2048] (consumed by k_cd before k_pv)
//  Aarr : 0x1480000 f32[16][2048]      128KB  exp2(f1*log2e)
//  Barr : 0x14A0000 f32                128KB  exp2(0.2*f1*log2e)
//  Cexp : 0x14C0000 f32                128KB  exp2(f2*log2e)
//  Dexp : 0x14E0000 f32                128KB  exp2(0.2*f2*log2e)
//  CD   : 0x1500000 u32[16][2048]      128KB  packed (bf16 C/D | bf16 Dbar/D)

__device__ __forceinline__ u16 f2bf(float f){
  union{float f; u32 u;} x; x.f = f;
  u32 r = x.u + 0x7FFFu + ((x.u >> 16) & 1u);
  return (u16)(r >> 16);
}
__device__ __forceinline__ u32 pkbf(float a, float b){
  __hip_bfloat162 h = __float22bfloat162_rn(float2{a, b});
  union{ __hip_bfloat162 h; u32 u; } cv; cv.h = h;
  return cv.u;
}
__device__ __forceinline__ float bflo(u32 cd){ union{u32 u; float f;} v; v.u = cd << 16; return v.f; }
__device__ __forceinline__ float bfhi(u32 cd){ union{u32 u; float f;} v; v.u = cd & 0xFFFF0000u; return v.f; }

// ---------------- K1: proj(+fdots) || pack ----------------
__global__ __launch_bounds__(256) void k_front(const float* __restrict__ x,
      const float* __restrict__ W, const float* __restrict__ a1, const float* __restrict__ a2,
      const int* __restrict__ adj,
      u8* __restrict__ adjb, u16* __restrict__ hT,
      float* __restrict__ Aarr, float* __restrict__ Barr,
      float* __restrict__ Cexp, float* __restrict__ Dexp){
  int bid = blockIdx.x, t = threadIdx.x;

  if (bid >= 512){                    // ---- pack: 8 adj elems -> 1 byte ----
    int idx = (bid - 512)*256 + t;
    const int4* ap = (const int4*)(adj + (size_t)idx*8);
    int4 v0 = ap[0], v1 = ap[1];
    u32 byte = (u32)(v0.x > 0)        | ((u32)(v0.y > 0) << 1)
             | ((u32)(v0.z > 0) << 2) | ((u32)(v0.w > 0) << 3)
             | ((u32)(v1.x > 0) << 4) | ((u32)(v1.y > 0) << 5)
             | ((u32)(v1.z > 0) << 6) | ((u32)(v1.w > 0) << 7);
    adjb[idx] = (u8)byte;
    return;
  }
  // ---- proj: h = x @ W[head cb]; block-local W transpose in LDS, XOR-swizzled ----
  __shared__ u16 WL[64*264];
  int rt = bid & 127, cb = bid >> 7;
  const float* Wh = W + (size_t)cb*16384;     // [256 c][64 f]
  #pragma unroll 4
  for (int p = 0; p < 16; p++){
    int idx = p*256 + t;
    float4 wv = ((const float4*)Wh)[idx];
    int off = idx*4; int c = off >> 6, f0 = off & 63;
    int cc = c ^ (((f0 >> 2) & 7) << 3);
    WL[(f0+0)*264 + cc] = f2bf(wv.x);
    WL[(f0+1)*264 + cc] = f2bf(wv.y);
    WL[(f0+2)*264 + cc] = f2bf(wv.z);
    WL[(f0+3)*264 + cc] = f2bf(wv.w);
  }
  __syncthreads();

  int w = t >> 6, l = t & 63;
  int rA = rt*64 + w*16 + (l & 15);
  int kg = (l >> 4) * 8;
  int rowq[4], rswq[4];
  #pragma unroll
  for (int q = 0; q < 4; q++){
    rowq[q] = q*16 + (l & 15);
    rswq[q] = ((rowq[q] >> 2) & 7) << 3;
  }
  f32x4 acc[4] = {};
  const float* xrow = x + (size_t)rA * 256;
  #pragma unroll
  for (int ks = 0; ks < 8; ks++){
    int c = ks*32 + kg;
    float4 xa = *(const float4*)(xrow + c);
    float4 xb = *(const float4*)(xrow + c + 4);
    union{u32 w[4]; short8 v;} A;
    A.w[0] = pkbf(xa.x, xa.y); A.w[1] = pkbf(xa.z, xa.w);
    A.w[2] = pkbf(xb.x, xb.y); A.w[3] = pkbf(xb.z, xb.w);
    #pragma unroll
    for (int q = 0; q < 4; q++){
      short8 Bf = *(const short8*)&WL[rowq[q]*264 + (c ^ rswq[q])];
      acc[q] = __builtin_amdgcn_mfma_f32_16x16x32_bf16(A.v, Bf, acc[q], 0, 0, 0);
    }
  }
  int rb = rt*64 + w*16 + (l >> 4)*4;
  int b = rb >> 11, n = rb & 2047;
  #pragma unroll
  for (int q = 0; q < 4; q++){
    int f = q*16 + (l & 15);
    u32 p0 = pkbf(acc[q][0], acc[q][1]);
    u32 p1 = pkbf(acc[q][2], acc[q][3]);
    u16* dst = hT + ((size_t)(b*4 + cb)*64 + f)*2048 + n;
    *(uint2*)dst = uint2{p0, p1};
  }
  float a1v[4], a2v[4];
  #pragma unroll
  for (int q = 0; q < 4; q++){
    a1v[q] = a1[cb*64 + q*16 + (l & 15)];
    a2v[q] = a2[cb*64 + q*16 + (l & 15)];
  }
  float s1[4], s2[4];
  #pragma unroll
  for (int r = 0; r < 4; r++){
    s1[r] = acc[0][r]*a1v[0] + acc[1][r]*a1v[1] + acc[2][r]*a1v[2] + acc[3][r]*a1v[3];
    s2[r] = acc[0][r]*a2v[0] + acc[1][r]*a2v[1] + acc[2][r]*a2v[2] + acc[3][r]*a2v[3];
  }
  #pragma unroll
  for (int m = 1; m <= 8; m <<= 1){
    #pragma unroll
    for (int r = 0; r < 4; r++){
      s1[r] += __shfl_xor(s1[r], m);
      s2[r] += __shfl_xor(s2[r], m);
    }
  }
  if ((l & 15) == 0){
    #pragma unroll
    for (int r = 0; r < 4; r++){
      int row = rb + r;
      int bb = row >> 11, nn = row & 2047;
      int o = (bb*4 + cb)*2048 + nn;
      float fa = s1[r] * LOG2E;
      Aarr[o] = __builtin_amdgcn_exp2f(fa);
      Barr[o] = __builtin_amdgcn_exp2f(0.2f*fa);
      float fb = s2[r] * LOG2E;
      Cexp[o] = __builtin_amdgcn_exp2f(fb);
      Dexp[o] = __builtin_amdgcn_exp2f(0.2f*fb);
    }
  }
}

// ---------------- K2: colsum partials (block = 64 j x 128 i x 16 bh) ----------------
__global__ __launch_bounds__(256) void k_colsum(const u32* __restrict__ adjw,
      const float* __restrict__ Aarr, const float* __restrict__ Barr,
      const float* __restrict__ Cexp, const float* __restrict__ Dexp,
      float* __restrict__ partial){
  __shared__ float AL[128*16], BL[128*16];   // [i][bh] f32, 16KB
  __shared__ float red[4][1024];             // [wave][bh*64+j] 16KB
  int jt = blockIdx.x;      // 32 j-tiles of 64
  int is = blockIdx.y;      // 16 i-segments of 128
  int t = threadIdx.x, w = t >> 6, l = t & 63;
  int i0 = is*128;
  // stage A/B as [i][bh] (coalesced reads along i)
  for (int k = t; k < 2048; k += 256){
    int bh = k >> 7, ii = k & 127;
    float av = Aarr[bh*2048 + i0 + ii];
    float bv = Barr[bh*2048 + i0 + ii];
    AL[ii*16 + bh] = av;
    BL[ii*16 + bh] = bv;
  }
  // per-lane C/D for all 16 bh
  int j = jt*64 + l;
  float Cj[16], Dj[16];
  #pragma unroll
  for (int bh = 0; bh < 16; bh++){
    Cj[bh] = Cexp[bh*2048 + j];
    Dj[bh] = Dexp[bh*2048 + j];
  }
  float acc[16] = {};
  __syncthreads();
  int wi = jt*2 + (l >> 5), sh = l & 31;
  const u32* aw = adjw + wi;
  #pragma unroll 2
  for (int ii = w*32; ii < w*32 + 32; ii++){
    u32 m = aw[(size_t)(i0 + ii)*64];
    float bitf = (float)((m >> sh) & 1u);
    const float* ar = &AL[ii*16];
    const float* br = &BL[ii*16];
    #pragma unroll
    for (int q = 0; q < 4; q++){
      float4 a4 = *(const float4*)(ar + q*4);
      float4 b4 = *(const float4*)(br + q*4);
      acc[q*4+0] = fmaf(fmaxf(a4.x*Cj[q*4+0], b4.x*Dj[q*4+0]), bitf, acc[q*4+0]);
      acc[q*4+1] = fmaf(fmaxf(a4.y*Cj[q*4+1], b4.y*Dj[q*4+1]), bitf, acc[q*4+1]);
      acc[q*4+2] = fmaf(fmaxf(a4.z*Cj[q*4+2], b4.z*Dj[q*4+2]), bitf, acc[q*4+2]);
      acc[q*4+3] = fmaf(fmaxf(a4.w*Cj[q*4+3], b4.w*Dj[q*4+3]), bitf, acc[q*4+3]);
    }
  }
  #pragma unroll
  for (int bh = 0; bh < 16; bh++) red[w][bh*64 + l] = acc[bh];
  __syncthreads();
  #pragma unroll
  for (int k = 0; k < 4; k++){
    int e = t*4 + k;                       // bh*64 + jloc
    float s = (red[0][e] + red[1][e]) + (red[2][e] + red[3][e]);
    int bh = e >> 6, jl = e & 63;
    partial[((size_t)is*16 + bh)*2048 + jt*64 + jl] = s;
  }
}

// ---------------- K3: k_cd — reduce partials, emit CD ----------------
__global__ __launch_bounds__(256) void k_cd(const float* __restrict__ partial,
      const float* __restrict__ Cexp, const float* __restrict__ Dexp,
      u32* __restrict__ CD){
  int t = blockIdx.x*256 + threadIdx.x;    // bh*2048 + j, 32768 total
  float s = 0.f;
  #pragma unroll
  for (int is = 0; is < 16; is++) s += partial[(size_t)is*32768 + t];
  float inv = 1.0f / s;
  CD[t] = pkbf(Cexp[t]*inv, Dexp[t]*inv);
}

// ---------------- K4: fused PV, 32 i/wave, j-split -> f32 partials ----------------
__global__ __launch_bounds__(256) void k_pv(const u32* __restrict__ adjw, const u16* __restrict__ hT,
      const float* __restrict__ Aarr, const float* __restrict__ Barr,
      const u32* __restrict__ CD, float* __restrict__ part){
  int it = blockIdx.x;           // 16 i-tiles of 128
  int bh = blockIdx.y;           // 16
  int jh = blockIdx.z;           // 2 j-halves
  int b = bh >> 2, h = bh & 3;
  int t = threadIdx.x;
  int w = t >> 6, l = t & 63;

  __shared__ u16 hTl[64*136];

  int i0 = it*128 + w*32 + (l & 15);
  float Ai0 = Aarr[bh*2048 + i0],      Bi0 = Barr[bh*2048 + i0];
  float Ai1 = Aarr[bh*2048 + i0 + 16], Bi1 = Barr[bh*2048 + i0 + 16];
  const u32* CDr = CD + bh*2048;
  const u16* hTr = hT + (size_t)bh * 64 * 2048;
  int kg = (l >> 4) * 8;
  f32x4 acc[2][4] = {};

  for (int jj = 0; jj < 1024; jj += 128){
    int jc = jh*1024 + jj;
    __syncthreads();
    {
      int f = t >> 2, seg = (t & 3) * 32;
      const u16* src = hTr + (size_t)f*2048 + jc + seg;
      u16* d = hTl + f*136 + seg;
      *(uint4*)(d)      = *(const uint4*)(src);
      *(uint4*)(d + 8)  = *(const uint4*)(src + 8);
      *(uint4*)(d + 16) = *(const uint4*)(src + 16);
      *(uint4*)(d + 24) = *(const uint4*)(src + 24);
    }
    __syncthreads();
    uint4 mw0 = *(const uint4*)(adjw + (size_t)i0*64 + (jc >> 5));
    uint4 mw1 = *(const uint4*)(adjw + (size_t)(i0+16)*64 + (jc >> 5));
    #pragma unroll
    for (int ks = 0; ks < 4; ks++){
      u32 cd[8];
      *(uint4*)(cd)     = *(const uint4*)(CDr + jc + ks*32 + kg);
      *(uint4*)(cd + 4) = *(const uint4*)(CDr + jc + ks*32 + kg + 4);
      u32 w0 = (&mw0.x)[ks] >> kg;
      u32 w1 = (&mw1.x)[ks] >> kg;
      float wv0[8], wv1[8];
      #pragma unroll
      for (int e = 0; e < 8; e++){
        float ca = bflo(cd[e]), db = bfhi(cd[e]);
        float ev0 = fmaxf(Ai0*ca, Bi0*db);
        float ev1 = fmaxf(Ai1*ca, Bi1*db);
        wv0[e] = ((int)(w0 << (31-e)) < 0) ? ev0 : 0.f;
        wv1[e] = ((int)(w1 << (31-e)) < 0) ? ev1 : 0.f;
      }
      union{u32 w[4]; short8 v;} A0, A1;
      A0.w[0] = pkbf(wv0[0], wv0[1]); A0.w[1] = pkbf(wv0[2], wv0[3]);
      A0.w[2] = pkbf(wv0[4], wv0[5]); A0.w[3] = pkbf(wv0[6], wv0[7]);
      A1.w[0] = pkbf(wv1[0], wv1[1]); A1.w[1] = pkbf(wv1[2], wv1[3]);
      A1.w[2] = pkbf(wv1[4], wv1[5]); A1.w[3] = pkbf(wv1[6], wv1[7]);
      #pragma unroll
      for (int q = 0; q < 4; q++){
        short8 Bf = *(const short8*)&hTl[(q*16 + (l & 15))*136 + ks*32 + kg];
        acc[0][q] = __builtin_amdgcn_mfma_f32_16x16x32_bf16(A0.v, Bf, acc[0][q], 0, 0, 0);
        acc[1][q] = __builtin_amdgcn_mfma_f32_16x16x32_bf16(A1.v, Bf, acc[1][q], 0, 0, 0);
      }
    }
  }
  float* pr = part + ((size_t)(jh*4 + b)*2048)*256;
  #pragma unroll
  for (int r = 0; r < 2; r++){
    int nb = it*128 + w*32 + r*16 + (l >> 4)*4;
    #pragma unroll
    for (int q = 0; q < 4; q++){
      int f = h*64 + q*16 + (l & 15);
      #pragma unroll
      for (int rr = 0; rr < 4; rr++){
        pr[(size_t)(nb + rr)*256 + f] = acc[r][q][rr];
      }
    }
  }
}

// ---------------- K5: out = leaky(relu(p0+p1) @ Wl^T + bl) ----------------
__global__ __launch_bounds__(256) void k_out(const float* __restrict__ part,
                       const float* __restrict__ Wl, const float* __restrict__ bl,
                       float* __restrict__ out){
  int rt = blockIdx.x;
  int w = threadIdx.x >> 6, l = threadIdx.x & 63;
  int rA = rt*64 + w*16 + (l & 15);
  int b = rA >> 11, n = rA & 2047;
  const float* p0 = part + ((size_t)b*2048 + n)*256;
  const float* p1 = part + ((size_t)(4 + b)*2048 + n)*256;
  int kg = (l >> 4) * 8;
  f32x4 acc[4] = {};
  #pragma unroll
  for (int ks = 0; ks < 8; ks++){
    int c = ks*32 + kg;
    float4 x0 = *(const float4*)(p0 + c);
    float4 x1 = *(const float4*)(p0 + c + 4);
    float4 y0 = *(const float4*)(p1 + c);
    float4 y1 = *(const float4*)(p1 + c + 4);
    float av[8];
    av[0] = fmaxf(x0.x + y0.x, 0.f); av[1] = fmaxf(x0.y + y0.y, 0.f);
    av[2] = fmaxf(x0.z + y0.z, 0.f); av[3] = fmaxf(x0.w + y0.w, 0.f);
    av[4] = fmaxf(x1.x + y1.x, 0.f); av[5] = fmaxf(x1.y + y1.y, 0.f);
    av[6] = fmaxf(x1.z + y1.z, 0.f); av[7] = fmaxf(x1.w + y1.w, 0.f);
    union{u32 w[4]; short8 v;} A;
    A.w[0] = pkbf(av[0], av[1]); A.w[1] = pkbf(av[2], av[3]);
    A.w[2] = pkbf(av[4], av[5]); A.w[3] = pkbf(av[6], av[7]);
    #pragma unroll
    for (int q = 0; q < 4; q++){
      const float* wr = Wl + (size_t)(q*16 + (l & 15))*256 + c;
      float4 u0 = *(const float4*)(wr);
      float4 u1 = *(const float4*)(wr + 4);
      union{u32 w[4]; short8 v;} Bv;
      Bv.w[0] = pkbf(u0.x, u0.y); Bv.w[1] = pkbf(u0.z, u0.w);
      Bv.w[2] = pkbf(u1.x, u1.y); Bv.w[3] = pkbf(u1.z, u1.w);
      acc[q] = __builtin_amdgcn_mfma_f32_16x16x32_bf16(A.v, Bv.v, acc[q], 0, 0, 0);
    }
  }
  int rb = rt*64 + w*16 + (l >> 4)*4;
  #pragma unroll
  for (int q = 0; q < 4; q++){
    int o = q*16 + (l & 15);
    float bv = bl[o];
    #pragma unroll
    for (int r = 0; r < 4; r++){
      float v = acc[q][r] + bv;
      out[(size_t)(rb + r)*64 + o] = fmaxf(v, 0.2f*v);
    }
  }
}

extern "C" void kernel_launch(void* const* d_in, const int* in_sizes, int n_in,
                              void* d_out, int out_size, void* d_ws, size_t ws_size,
                              hipStream_t stream) {
  const float* x  = (const float*)d_in[0];
  const int* adj  = (const int*)d_in[1];
  const float* W  = (const float*)d_in[2];
  const float* a1 = (const float*)d_in[3];
  const float* a2 = (const float*)d_in[4];
  const float* Wl = (const float*)d_in[5];
  const float* bl = (const float*)d_in[6];
  float* out = (float*)d_out;
  char* ws = (char*)d_ws;

  u32* adjw    = (u32*)(ws + 0x0000000);
  u16* hT      = (u16*)(ws + 0x0080000);
  float* part  = (float*)(ws + 0x0480000);   // pv partials; first 2MB = colsum partials
  float* Aarr  = (float*)(ws + 0x1480000);
  float* Barr  = (float*)(ws + 0x14A0000);
  float* Cexp  = (float*)(ws + 0x14C0000);
  float* Dexp  = (float*)(ws + 0x14E0000);
  u32* CD      = (u32*)(ws + 0x1500000);

  k_front<<<2560, 256, 0, stream>>>(x, W, a1, a2, adj, (u8*)adjw, hT, Aarr, Barr, Cexp, Dexp);
  k_colsum<<<dim3(32, 16), 256, 0, stream>>>(adjw, Aarr, Barr, Cexp, Dexp, part);
  k_cd<<<128, 256, 0, stream>>>(part, Cexp, Dexp, CD);
  k_pv<<<dim3(16, 16, 2), 256, 0, stream>>>(adjw, hT, Aarr, Barr, CD, part);
  k_out<<<128, 256, 0, stream>>>(part, Wl, bl, out);
}

// Round 8
// 73.261 us; speedup vs baseline: 3.7618x; 1.0600x over previous
//
#include <hip/hip_runtime.h>
#include <hip/hip_bf16.h>
#include <stdint.h>

typedef __attribute__((ext_vector_type(8))) short short8;
typedef __attribute__((ext_vector_type(4))) float f32x4;
typedef uint32_t u32;
typedef uint16_t u16;
typedef uint8_t u8;

#define LOG2E 1.4426950408889634f

// B=4, N=2048, Cin=256, F=64, H=4
// Pipeline (4 kernels):
//  K1 k_front : proj (x@W per head via MFMA, W transposed block-locally in LDS,
//               XOR-swizzled) + fused exact-fp32 fdots -> Aarr/Barr/Cexp/Dexp
//               || pack adj bits || zero Dsum
//  K2 k_colsum: block (jt, iseg) = 64 j x 128 i x 16 bh, inner loop over bh;
//               cross-wave LDS reduce, then atomicAdd into Dsum[bh][j]
//  K3 k_pv    : per-block CD slice computed inline into LDS from Cexp/Dexp/Dsum;
//               P in-register (32 i/wave), j-split -> f32 partials
//  K4 k_out   : out = leaky((relu(p0+p1) @ Wl^T) + bl)
//
// ws layout (bytes):
//  adjw : 0x0000000 u32[2048*64]       512KB  packed adjacency bits
//  hT   : 0x0080000 bf16[16][64][2048]   4MB  per-(b,h) h transposed [f][n]
//  part : 0x0480000 f32[2][4][2048][256] 16MB pv partials (2 j-halves)
//  Aarr : 0x1480000 f32[16][2048]      128KB  exp(f1)
//  Barr : 0x14A0000 f32                128KB  exp(0.2*f1)
//  Cexp : 0x14C0000 f32                128KB  exp(f2)
//  Dexp : 0x14E0000 f32                128KB  exp(0.2*f2)
//  Dsum : 0x1500000 f32[16][2048]      128KB  column sums (atomic)

__device__ __forceinline__ u16 f2bf(float f){
  union{float f; u32 u;} x; x.f = f;
  u32 r = x.u + 0x7FFFu + ((x.u >> 16) & 1u);
  return (u16)(r >> 16);
}
__device__ __forceinline__ u32 pkbf(float a, float b){
  __hip_bfloat162 h = __float22bfloat162_rn(float2{a, b});
  union{ __hip_bfloat162 h; u32 u; } cv; cv.h = h;
  return cv.u;
}
__device__ __forceinline__ float bflo(u32 cd){ union{u32 u; float f;} v; v.u = cd << 16; return v.f; }
__device__ __forceinline__ float bfhi(u32 cd){ union{u32 u; float f;} v; v.u = cd & 0xFFFF0000u; return v.f; }

// ---------------- K1: proj(+fdots) || pack || zero Dsum ----------------
__global__ __launch_bounds__(256) void k_front(const float* __restrict__ x,
      const float* __restrict__ W, const float* __restrict__ a1, const float* __restrict__ a2,
      const int* __restrict__ adj,
      u8* __restrict__ adjb, u16* __restrict__ hT,
      float* __restrict__ Aarr, float* __restrict__ Barr,
      float* __restrict__ Cexp, float* __restrict__ Dexp,
      float* __restrict__ Dsum){
  int bid = blockIdx.x, t = threadIdx.x;

  if (bid >= 2560){                   // ---- zero Dsum: 128 blocks x 256 = 32768 ----
    Dsum[(bid - 2560)*256 + t] = 0.f;
    return;
  }
  if (bid >= 512){                    // ---- pack: 8 adj elems -> 1 byte ----
    int idx = (bid - 512)*256 + t;
    const int4* ap = (const int4*)(adj + (size_t)idx*8);
    int4 v0 = ap[0], v1 = ap[1];
    u32 byte = (u32)(v0.x > 0)        | ((u32)(v0.y > 0) << 1)
             | ((u32)(v0.z > 0) << 2) | ((u32)(v0.w > 0) << 3)
             | ((u32)(v1.x > 0) << 4) | ((u32)(v1.y > 0) << 5)
             | ((u32)(v1.z > 0) << 6) | ((u32)(v1.w > 0) << 7);
    adjb[idx] = (u8)byte;
    return;
  }
  // ---- proj: h = x @ W[head cb]; block-local W transpose in LDS, XOR-swizzled ----
  __shared__ u16 WL[64*264];
  int rt = bid & 127, cb = bid >> 7;
  const float* Wh = W + (size_t)cb*16384;     // [256 c][64 f]
  #pragma unroll 4
  for (int p = 0; p < 16; p++){
    int idx = p*256 + t;
    float4 wv = ((const float4*)Wh)[idx];
    int off = idx*4; int c = off >> 6, f0 = off & 63;
    int cc = c ^ (((f0 >> 2) & 7) << 3);
    WL[(f0+0)*264 + cc] = f2bf(wv.x);
    WL[(f0+1)*264 + cc] = f2bf(wv.y);
    WL[(f0+2)*264 + cc] = f2bf(wv.z);
    WL[(f0+3)*264 + cc] = f2bf(wv.w);
  }
  __syncthreads();

  int w = t >> 6, l = t & 63;
  int rA = rt*64 + w*16 + (l & 15);
  int kg = (l >> 4) * 8;
  int rowq[4], rswq[4];
  #pragma unroll
  for (int q = 0; q < 4; q++){
    rowq[q] = q*16 + (l & 15);
    rswq[q] = ((rowq[q] >> 2) & 7) << 3;
  }
  f32x4 acc[4] = {};
  const float* xrow = x + (size_t)rA * 256;
  #pragma unroll
  for (int ks = 0; ks < 8; ks++){
    int c = ks*32 + kg;
    float4 xa = *(const float4*)(xrow + c);
    float4 xb = *(const float4*)(xrow + c + 4);
    union{u32 w[4]; short8 v;} A;
    A.w[0] = pkbf(xa.x, xa.y); A.w[1] = pkbf(xa.z, xa.w);
    A.w[2] = pkbf(xb.x, xb.y); A.w[3] = pkbf(xb.z, xb.w);
    #pragma unroll
    for (int q = 0; q < 4; q++){
      short8 Bf = *(const short8*)&WL[rowq[q]*264 + (c ^ rswq[q])];
      acc[q] = __builtin_amdgcn_mfma_f32_16x16x32_bf16(A.v, Bf, acc[q], 0, 0, 0);
    }
  }
  int rb = rt*64 + w*16 + (l >> 4)*4;
  int b = rb >> 11, n = rb & 2047;
  #pragma unroll
  for (int q = 0; q < 4; q++){
    int f = q*16 + (l & 15);
    u32 p0 = pkbf(acc[q][0], acc[q][1]);
    u32 p1 = pkbf(acc[q][2], acc[q][3]);
    u16* dst = hT + ((size_t)(b*4 + cb)*64 + f)*2048 + n;
    *(uint2*)dst = uint2{p0, p1};
  }
  float a1v[4], a2v[4];
  #pragma unroll
  for (int q = 0; q < 4; q++){
    a1v[q] = a1[cb*64 + q*16 + (l & 15)];
    a2v[q] = a2[cb*64 + q*16 + (l & 15)];
  }
  float s1[4], s2[4];
  #pragma unroll
  for (int r = 0; r < 4; r++){
    s1[r] = acc[0][r]*a1v[0] + acc[1][r]*a1v[1] + acc[2][r]*a1v[2] + acc[3][r]*a1v[3];
    s2[r] = acc[0][r]*a2v[0] + acc[1][r]*a2v[1] + acc[2][r]*a2v[2] + acc[3][r]*a2v[3];
  }
  #pragma unroll
  for (int m = 1; m <= 8; m <<= 1){
    #pragma unroll
    for (int r = 0; r < 4; r++){
      s1[r] += __shfl_xor(s1[r], m);
      s2[r] += __shfl_xor(s2[r], m);
    }
  }
  if ((l & 15) == 0){
    #pragma unroll
    for (int r = 0; r < 4; r++){
      int row = rb + r;
      int bb = row >> 11, nn = row & 2047;
      int o = (bb*4 + cb)*2048 + nn;
      float fa = s1[r] * LOG2E;
      Aarr[o] = __builtin_amdgcn_exp2f(fa);
      Barr[o] = __builtin_amdgcn_exp2f(0.2f*fa);
      float fb = s2[r] * LOG2E;
      Cexp[o] = __builtin_amdgcn_exp2f(fb);
      Dexp[o] = __builtin_amdgcn_exp2f(0.2f*fb);
    }
  }
}

// ---------------- K2: colsum (block = 64 j x 128 i x 16 bh) -> atomic Dsum ----------------
__global__ __launch_bounds__(256) void k_colsum(const u32* __restrict__ adjw,
      const float* __restrict__ Aarr, const float* __restrict__ Barr,
      const float* __restrict__ Cexp, const float* __restrict__ Dexp,
      float* __restrict__ Dsum){
  __shared__ float AL[128*16], BL[128*16];   // [i][bh] f32, 16KB
  __shared__ float red[4][1024];             // [wave][bh*64+j] 16KB
  int jt = blockIdx.x;      // 32 j-tiles of 64
  int is = blockIdx.y;      // 16 i-segments of 128
  int t = threadIdx.x, w = t >> 6, l = t & 63;
  int i0 = is*128;
  for (int k = t; k < 2048; k += 256){
    int bh = k >> 7, ii = k & 127;
    AL[ii*16 + bh] = Aarr[bh*2048 + i0 + ii];
    BL[ii*16 + bh] = Barr[bh*2048 + i0 + ii];
  }
  int j = jt*64 + l;
  float Cj[16], Dj[16];
  #pragma unroll
  for (int bh = 0; bh < 16; bh++){
    Cj[bh] = Cexp[bh*2048 + j];
    Dj[bh] = Dexp[bh*2048 + j];
  }
  float acc[16] = {};
  __syncthreads();
  int wi = jt*2 + (l >> 5), sh = l & 31;
  const u32* aw = adjw + wi;
  #pragma unroll 2
  for (int ii = w*32; ii < w*32 + 32; ii++){
    u32 m = aw[(size_t)(i0 + ii)*64];
    float bitf = (float)((m >> sh) & 1u);
    const float* ar = &AL[ii*16];
    const float* br = &BL[ii*16];
    #pragma unroll
    for (int q = 0; q < 4; q++){
      float4 a4 = *(const float4*)(ar + q*4);
      float4 b4 = *(const float4*)(br + q*4);
      acc[q*4+0] = fmaf(fmaxf(a4.x*Cj[q*4+0], b4.x*Dj[q*4+0]), bitf, acc[q*4+0]);
      acc[q*4+1] = fmaf(fmaxf(a4.y*Cj[q*4+1], b4.y*Dj[q*4+1]), bitf, acc[q*4+1]);
      acc[q*4+2] = fmaf(fmaxf(a4.z*Cj[q*4+2], b4.z*Dj[q*4+2]), bitf, acc[q*4+2]);
      acc[q*4+3] = fmaf(fmaxf(a4.w*Cj[q*4+3], b4.w*Dj[q*4+3]), bitf, acc[q*4+3]);
    }
  }
  #pragma unroll
  for (int bh = 0; bh < 16; bh++) red[w][bh*64 + l] = acc[bh];
  __syncthreads();
  #pragma unroll
  for (int k = 0; k < 4; k++){
    int e = t*4 + k;                       // bh*64 + jloc
    float s = (red[0][e] + red[1][e]) + (red[2][e] + red[3][e]);
    int bh = e >> 6, jl = e & 63;
    atomicAdd(&Dsum[bh*2048 + jt*64 + jl], s);
  }
}

// ---------------- K3: fused PV; CD slice inline in LDS; j-split -> f32 partials ----------------
__global__ __launch_bounds__(256) void k_pv(const u32* __restrict__ adjw, const u16* __restrict__ hT,
      const float* __restrict__ Aarr, const float* __restrict__ Barr,
      const float* __restrict__ Cexp, const float* __restrict__ Dexp,
      const float* __restrict__ Dsum, float* __restrict__ part){
  int it = blockIdx.x;           // 16 i-tiles of 128
  int bh = blockIdx.y;           // 16
  int jh = blockIdx.z;           // 2 j-halves
  int b = bh >> 2, h = bh & 3;
  int t = threadIdx.x;
  int w = t >> 6, l = t & 63;

  __shared__ u16 hTl[64*136];    // 17.4KB
  __shared__ u32 CDl[1024];      // 4KB: packed (C/D | Dbar/D) for this j-half

  {  // inline CD: 4 j per thread
    int gj = bh*2048 + jh*1024 + t*4;
    float4 c4 = *(const float4*)(Cexp + gj);
    float4 d4 = *(const float4*)(Dexp + gj);
    float4 s4 = *(const float4*)(Dsum + gj);
    float i0v = 1.0f/s4.x, i1v = 1.0f/s4.y, i2v = 1.0f/s4.z, i3v = 1.0f/s4.w;
    uint4 pk;
    pk.x = pkbf(c4.x*i0v, d4.x*i0v);
    pk.y = pkbf(c4.y*i1v, d4.y*i1v);
    pk.z = pkbf(c4.z*i2v, d4.z*i2v);
    pk.w = pkbf(c4.w*i3v, d4.w*i3v);
    *(uint4*)&CDl[t*4] = pk;
  }

  int i0 = it*128 + w*32 + (l & 15);
  float Ai0 = Aarr[bh*2048 + i0],      Bi0 = Barr[bh*2048 + i0];
  float Ai1 = Aarr[bh*2048 + i0 + 16], Bi1 = Barr[bh*2048 + i0 + 16];
  const u16* hTr = hT + (size_t)bh * 64 * 2048;
  int kg = (l >> 4) * 8;
  f32x4 acc[2][4] = {};

  for (int jj = 0; jj < 1024; jj += 128){
    int jc = jh*1024 + jj;
    __syncthreads();
    {
      int f = t >> 2, seg = (t & 3) * 32;
      const u16* src = hTr + (size_t)f*2048 + jc + seg;
      u16* d = hTl + f*136 + seg;
      *(uint4*)(d)      = *(const uint4*)(src);
      *(uint4*)(d + 8)  = *(const uint4*)(src + 8);
      *(uint4*)(d + 16) = *(const uint4*)(src + 16);
      *(uint4*)(d + 24) = *(const uint4*)(src + 24);
    }
    __syncthreads();
    uint4 mw0 = *(const uint4*)(adjw + (size_t)i0*64 + (jc >> 5));
    uint4 mw1 = *(const uint4*)(adjw + (size_t)(i0+16)*64 + (jc >> 5));
    #pragma unroll
    for (int ks = 0; ks < 4; ks++){
      u32 cd[8];
      *(uint4*)(cd)     = *(const uint4*)&CDl[jj + ks*32 + kg];
      *(uint4*)(cd + 4) = *(const uint4*)&CDl[jj + ks*32 + kg + 4];
      u32 w0 = (&mw0.x)[ks] >> kg;
      u32 w1 = (&mw1.x)[ks] >> kg;
      float wv0[8], wv1[8];
      #pragma unroll
      for (int e = 0; e < 8; e++){
        float ca = bflo(cd[e]), db = bfhi(cd[e]);
        float ev0 = fmaxf(Ai0*ca, Bi0*db);
        float ev1 = fmaxf(Ai1*ca, Bi1*db);
        wv0[e] = ((int)(w0 << (31-e)) < 0) ? ev0 : 0.f;
        wv1[e] = ((int)(w1 << (31-e)) < 0) ? ev1 : 0.f;
      }
      union{u32 w[4]; short8 v;} A0, A1;
      A0.w[0] = pkbf(wv0[0], wv0[1]); A0.w[1] = pkbf(wv0[2], wv0[3]);
      A0.w[2] = pkbf(wv0[4], wv0[5]); A0.w[3] = pkbf(wv0[6], wv0[7]);
      A1.w[0] = pkbf(wv1[0], wv1[1]); A1.w[1] = pkbf(wv1[2], wv1[3]);
      A1.w[2] = pkbf(wv1[4], wv1[5]); A1.w[3] = pkbf(wv1[6], wv1[7]);
      #pragma unroll
      for (int q = 0; q < 4; q++){
        short8 Bf = *(const short8*)&hTl[(q*16 + (l & 15))*136 + ks*32 + kg];
        acc[0][q] = __builtin_amdgcn_mfma_f32_16x16x32_bf16(A0.v, Bf, acc[0][q], 0, 0, 0);
        acc[1][q] = __builtin_amdgcn_mfma_f32_16x16x32_bf16(A1.v, Bf, acc[1][q], 0, 0, 0);
      }
    }
  }
  float* pr = part + ((size_t)(jh*4 + b)*2048)*256;
  #pragma unroll
  for (int r = 0; r < 2; r++){
    int nb = it*128 + w*32 + r*16 + (l >> 4)*4;
    #pragma unroll
    for (int q = 0; q < 4; q++){
      int f = h*64 + q*16 + (l & 15);
      #pragma unroll
      for (int rr = 0; rr < 4; rr++){
        pr[(size_t)(nb + rr)*256 + f] = acc[r][q][rr];
      }
    }
  }
}

// ---------------- K4: out = leaky(relu(p0+p1) @ Wl^T + bl) ----------------
__global__ __launch_bounds__(256) void k_out(const float* __restrict__ part,
                       const float* __restrict__ Wl, const float* __restrict__ bl,
                       float* __restrict__ out){
  int rt = blockIdx.x;
  int w = threadIdx.x >> 6, l = threadIdx.x & 63;
  int rA = rt*64 + w*16 + (l & 15);
  int b = rA >> 11, n = rA & 2047;
  const float* p0 = part + ((size_t)b*2048 + n)*256;
  const float* p1 = part + ((size_t)(4 + b)*2048 + n)*256;
  int kg = (l >> 4) * 8;
  f32x4 acc[4] = {};
  #pragma unroll
  for (int ks = 0; ks < 8; ks++){
    int c = ks*32 + kg;
    float4 x0 = *(const float4*)(p0 + c);
    float4 x1 = *(const float4*)(p0 + c + 4);
    float4 y0 = *(const float4*)(p1 + c);
    float4 y1 = *(const float4*)(p1 + c + 4);
    float av[8];
    av[0] = fmaxf(x0.x + y0.x, 0.f); av[1] = fmaxf(x0.y + y0.y, 0.f);
    av[2] = fmaxf(x0.z + y0.z, 0.f); av[3] = fmaxf(x0.w + y0.w, 0.f);
    av[4] = fmaxf(x1.x + y1.x, 0.f); av[5] = fmaxf(x1.y + y1.y, 0.f);
    av[6] = fmaxf(x1.z + y1.z, 0.f); av[7] = fmaxf(x1.w + y1.w, 0.f);
    union{u32 w[4]; short8 v;} A;
    A.w[0] = pkbf(av[0], av[1]); A.w[1] = pkbf(av[2], av[3]);
    A.w[2] = pkbf(av[4], av[5]); A.w[3] = pkbf(av[6], av[7]);
    #pragma unroll
    for (int q = 0; q < 4; q++){
      const float* wr = Wl + (size_t)(q*16 + (l & 15))*256 + c;
      float4 u0 = *(const float4*)(wr);
      float4 u1 = *(const float4*)(wr + 4);
      union{u32 w[4]; short8 v;} Bv;
      Bv.w[0] = pkbf(u0.x, u0.y); Bv.w[1] = pkbf(u0.z, u0.w);
      Bv.w[2] = pkbf(u1.x, u1.y); Bv.w[3] = pkbf(u1.z, u1.w);
      acc[q] = __builtin_amdgcn_mfma_f32_16x16x32_bf16(A.v, Bv.v, acc[q], 0, 0, 0);
    }
  }
  int rb = rt*64 + w*16 + (l >> 4)*4;
  #pragma unroll
  for (int q = 0; q < 4; q++){
    int o = q*16 + (l & 15);
    float bv = bl[o];
    #pragma unroll
    for (int r = 0; r < 4; r++){
      float v = acc[q][r] + bv;
      out[(size_t)(rb + r)*64 + o] = fmaxf(v, 0.2f*v);
    }
  }
}

extern "C" void kernel_launch(void* const* d_in, const int* in_sizes, int n_in,
                              void* d_out, int out_size, void* d_ws, size_t ws_size,
                              hipStream_t stream) {
  const float* x  = (const float*)d_in[0];
  const int* adj  = (const int*)d_in[1];
  const float* W  = (const float*)d_in[2];
  const float* a1 = (const float*)d_in[3];
  const float* a2 = (const float*)d_in[4];
  const float* Wl = (const float*)d_in[5];
  const float* bl = (const float*)d_in[6];
  float* out = (float*)d_out;
  char* ws = (char*)d_ws;

  u32* adjw    = (u32*)(ws + 0x0000000);
  u16* hT      = (u16*)(ws + 0x0080000);
  float* part  = (float*)(ws + 0x0480000);
  float* Aarr  = (float*)(ws + 0x1480000);
  float* Barr  = (float*)(ws + 0x14A0000);
  float* Cexp  = (float*)(ws + 0x14C0000);
  float* Dexp  = (float*)(ws + 0x14E0000);
  float* Dsum  = (float*)(ws + 0x1500000);

  k_front<<<2688, 256, 0, stream>>>(x, W, a1, a2, adj, (u8*)adjw, hT, Aarr, Barr, Cexp, Dexp, Dsum);
  k_colsum<<<dim3(32, 16), 256, 0, stream>>>(adjw, Aarr, Barr, Cexp, Dexp, Dsum);
  k_pv<<<dim3(16, 16, 2), 256, 0, stream>>>(adjw, hT, Aarr, Barr, Cexp, Dexp, Dsum, part);
  k_out<<<128, 256, 0, stream>>>(part, Wl, bl, out);
}